// Round 9
// baseline (22.267 us; speedup 1.0000x reference)
//
#include <hip/hip_runtime.h>
#include <math.h>

#define BB 64
#define LL 131072
#define NF 8
#define FLEN 31

#define TPB 64                  // one wave per workgroup: no barriers at all
#define RPT 8
#define TILE (TPB * RPT)        // 512 outputs per block
#define TCELLS (TILE / 4)       // 128 float4 cells per tile
#define NCELLS (TCELLS + 8)     // 136 staged cells (halo 4 each side)
#define ROWCELLS (LL / 4)       // 32768 cells per row

typedef float f32x4 __attribute__((ext_vector_type(4)));

// XOR swizzle on float4-cell index (involution within 64-cell groups):
// dense writes (c = base+lane) and strided reads (c = 2*lane+k) both spread
// uniformly across the 8 4-bank groups -> conflict-free b128.
#define SWZ(c) ((c) ^ (((c) >> 3) & 7))

__global__ __launch_bounds__(TPB) void adaptive_filter_fused(
    const float* __restrict__ x,
    const float* __restrict__ features,
    const float* __restrict__ fp,      // (NF, 1, FLEN)
    const float* __restrict__ W1,
    const float* __restrict__ b1,
    const float* __restrict__ W2,
    const float* __restrict__ b2,
    float* __restrict__ out)
{
    const int tiles_per_row = LL / TILE;            // 256
    const int row  = blockIdx.x / tiles_per_row;
    const int tile = blockIdx.x % tiles_per_row;
    const int ln   = threadIdx.x;                   // lane 0..63

    __shared__ f32x4 lds4[NCELLS];                  // 2.2 KB

    const f32x4* xrow4 = reinterpret_cast<const f32x4*>(x + (size_t)row * LL);
    const int wcell0 = tile * TCELLS;
    const int cell_base = wcell0 - 4;               // staged range [base, base+136)

    // ---- issue staging loads early (nt; zero-fill outside row) ----
    const int d0 = ln, d1 = ln + 64;
    const unsigned gc0 = (unsigned)(cell_base + d0);
    const unsigned gc1 = (unsigned)(cell_base + d1);
    const unsigned gc2 = (unsigned)(cell_base + ln + 128);
    f32x4 v0 = (f32x4)(0.0f);
    f32x4 v1 = v0, v2 = v0;
    if (gc0 < ROWCELLS) v0 = __builtin_nontemporal_load(&xrow4[gc0]);
    if (gc1 < ROWCELLS) v1 = __builtin_nontemporal_load(&xrow4[gc1]);
    const bool has2 = (ln < NCELLS - 128);          // lanes 0..7
    if (has2 && gc2 < ROWCELLS) v2 = __builtin_nontemporal_load(&xrow4[gc2]);

    // ---- taps MLP, branch-free on all 64 lanes (overlaps load latency) ----
    // lane ln computes tap index t = min(ln, 30); lanes 31..63 duplicate t=30.
    const int t = ln < FLEN ? ln : (FLEN - 1);
    float taps_mine;
    {
        float f[NF];
        #pragma unroll
        for (int j = 0; j < NF; ++j) f[j] = features[row * NF + j];

        float h[NF];
        #pragma unroll
        for (int i = 0; i < NF; ++i) {
            float s = b1[i];
            #pragma unroll
            for (int j = 0; j < NF; ++j) s = fmaf(f[j], W1[i * NF + j], s);
            h[i] = fmaxf(s, 0.0f);
        }

        float w[NF];
        float m = -1e30f;
        #pragma unroll
        for (int i = 0; i < NF; ++i) {
            float s = b2[i];
            #pragma unroll
            for (int j = 0; j < NF; ++j) s = fmaf(h[j], W2[i * NF + j], s);
            w[i] = s;
            m = fmaxf(m, s);
        }
        float denom = 0.0f;
        #pragma unroll
        for (int i = 0; i < NF; ++i) { w[i] = expf(w[i] - m); denom += w[i]; }
        const float inv = 1.0f / denom;

        float s = 0.0f;
        #pragma unroll
        for (int ff = 0; ff < NF; ++ff) s = fmaf(w[ff] * inv, fp[ff * FLEN + t], s);
        taps_mine = s;
    }

    // ---- taps to SGPRs: pure readlane broadcast (no LDS, exec is full) ----
    float tap[FLEN];
    #pragma unroll
    for (int k = 0; k < FLEN; ++k)
        tap[k] = __int_as_float(__builtin_amdgcn_readlane(__float_as_int(taps_mine), k));

    // ---- LDS staging writes (swizzled placement); same-wave ordering only ----
    lds4[SWZ(d0)] = v0;
    lds4[SWZ(d1)] = v1;
    if (has2) lds4[SWZ(ln + 128)] = v2;

    // ---- window: 10 swizzled b128 reads -> 40 floats, two halves ----
    // w[j] = x[row, 4*wcell0 + 8*ln - 16 + j], j = 0..39  (cells 2ln..2ln+9)
    float wA[20], wB[20];
    #pragma unroll
    for (int k = 0; k < 5; ++k) {
        const f32x4 v = lds4[SWZ(2 * ln + k)];
        wA[4 * k + 0] = v.x; wA[4 * k + 1] = v.y;
        wA[4 * k + 2] = v.z; wA[4 * k + 3] = v.w;
    }
    #pragma unroll
    for (int k = 0; k < 5; ++k) {
        const f32x4 v = lds4[SWZ(2 * ln + 5 + k)];
        wB[4 * k + 0] = v.x; wB[4 * k + 1] = v.y;
        wB[4 * k + 2] = v.z; wB[4 * k + 3] = v.w;
    }

    // out[4*wcell0 + 8*ln + r] = sum_t tap[t] * w[r + 1 + t]
    float acc[RPT];
    #pragma unroll
    for (int r = 0; r < RPT; ++r) acc[r] = 0.0f;

    #pragma unroll
    for (int r = 0; r < RPT; ++r) {
        #pragma unroll
        for (int k = 0; k <= 18 - r; ++k)          // j = r+1+k <= 19
            acc[r] = fmaf(tap[k], wA[r + 1 + k], acc[r]);
        #pragma unroll
        for (int k = 19 - r; k < FLEN; ++k)        // j-20 = r+k-19 in [0, r+11]
            acc[r] = fmaf(tap[k], wB[r + k - 19], acc[r]);
    }

    // ---- direct stores: two float4 per lane (32B stride), non-temporal ----
    f32x4* orow4 = reinterpret_cast<f32x4*>(out + (size_t)row * LL) + wcell0;
    f32x4 s0; s0.x = acc[0]; s0.y = acc[1]; s0.z = acc[2]; s0.w = acc[3];
    f32x4 s1; s1.x = acc[4]; s1.y = acc[5]; s1.z = acc[6]; s1.w = acc[7];
    __builtin_nontemporal_store(s0, &orow4[2 * ln + 0]);
    __builtin_nontemporal_store(s1, &orow4[2 * ln + 1]);
}

extern "C" void kernel_launch(void* const* d_in, const int* in_sizes, int n_in,
                              void* d_out, int out_size, void* d_ws, size_t ws_size,
                              hipStream_t stream) {
    const float* x        = (const float*)d_in[0];
    const float* features = (const float*)d_in[1];
    const float* fp       = (const float*)d_in[2];
    const float* W1       = (const float*)d_in[3];
    const float* b1       = (const float*)d_in[4];
    const float* W2       = (const float*)d_in[5];
    const float* b2       = (const float*)d_in[6];
    float* out = (float*)d_out;

    const int grid = BB * (LL / TILE);  // 64 * 256 = 16384 blocks
    adaptive_filter_fused<<<grid, TPB, 0, stream>>>(x, features, fp, W1, b1, W2, b2, out);
}

// Round 10
// 19.184 us; speedup vs baseline: 1.1607x; 1.1607x over previous
//
#include <hip/hip_runtime.h>
#include <math.h>

#define BB 64
#define LL 131072
#define NF 8
#define FLEN 31

#define TPB 256
#define RPT 8
#define TILE (TPB * RPT)        // 2048 outputs per tile
#define TCELLS (TILE / 4)       // 512 float4 cells per tile
#define NCELLS (TCELLS + 8)     // 520 staged cells (halo 4 each side)
#define NTILE 4                 // tiles per block (software pipeline depth)
#define GRPS (LL / TILE / NTILE) // 16 tile-groups per row
#define ROWCELLS (LL / 4)       // 32768 cells per row

typedef float f32x4 __attribute__((ext_vector_type(4)));

// XOR swizzle on float4-cell index (involution within 64-cell groups):
// dense writes (c = base+l) and strided reads (c = 2l+const) both spread
// uniformly: 8 lanes per 4-bank group = conflict-free b128.
#define SWZ(c) ((c) ^ (((c) >> 3) & 7))

// Raw barrier with LDS-only drain: global loads/stores stay in flight
// across it (unlike __syncthreads' vmcnt(0) drain). sched_barrier fences
// stop the compiler moving ds ops across it (rule #18 discipline).
#define LIGHT_BARRIER() do {                                  \
    __builtin_amdgcn_sched_barrier(0);                        \
    asm volatile("s_waitcnt lgkmcnt(0)" ::: "memory");        \
    __builtin_amdgcn_s_barrier();                             \
    __builtin_amdgcn_sched_barrier(0);                        \
} while (0)

__global__ __launch_bounds__(TPB, 4) void adaptive_filter_fused(
    const float* __restrict__ x,
    const float* __restrict__ features,
    const float* __restrict__ fp,      // (NF, 1, FLEN)
    const float* __restrict__ W1,
    const float* __restrict__ b1,
    const float* __restrict__ W2,
    const float* __restrict__ b2,
    float* __restrict__ out)
{
    const int row = blockIdx.x / GRPS;              // batch index
    const int grp = blockIdx.x % GRPS;              // tile-group within row
    const int tid = threadIdx.x;

    __shared__ f32x4 lds4[2][NCELLS];               // 16.6 KB double buffer
    __shared__ float cs[32];

    const f32x4* xrow4 = reinterpret_cast<const f32x4*>(x + (size_t)row * LL);
    f32x4* orowbase4 = reinterpret_cast<f32x4*>(out + (size_t)row * LL);

    const int d0 = tid, d1 = tid + TPB, d2 = tid + 2 * TPB;
    const bool has2 = (tid < NCELLS - 2 * TPB);     // lanes 0..7

    // ---- prologue: issue tile-0 staging loads (nt; zero-fill outside row) ----
    f32x4 pv0 = (f32x4)(0.0f), pv1 = pv0, pv2 = pv0;
    {
        const int cb = (grp * NTILE) * TCELLS - 4;
        const unsigned g0 = (unsigned)(cb + d0);
        const unsigned g1 = (unsigned)(cb + d1);
        const unsigned g2 = (unsigned)(cb + d2);
        if (g0 < ROWCELLS) pv0 = __builtin_nontemporal_load(&xrow4[g0]);
        if (g1 < ROWCELLS) pv1 = __builtin_nontemporal_load(&xrow4[g1]);
        if (has2 && g2 < ROWCELLS) pv2 = __builtin_nontemporal_load(&xrow4[g2]);
    }

    // ---- taps MLP on lanes < 31, once per block (overlaps load latency) ----
    if (tid < FLEN) {
        const int t = tid;
        float f[NF];
        #pragma unroll
        for (int j = 0; j < NF; ++j) f[j] = features[row * NF + j];

        float h[NF];
        #pragma unroll
        for (int i = 0; i < NF; ++i) {
            float s = b1[i];
            #pragma unroll
            for (int j = 0; j < NF; ++j) s = fmaf(f[j], W1[i * NF + j], s);
            h[i] = fmaxf(s, 0.0f);
        }

        float w[NF];
        float m = -1e30f;
        #pragma unroll
        for (int i = 0; i < NF; ++i) {
            float s = b2[i];
            #pragma unroll
            for (int j = 0; j < NF; ++j) s = fmaf(h[j], W2[i * NF + j], s);
            w[i] = s;
            m = fmaxf(m, s);
        }
        float denom = 0.0f;
        #pragma unroll
        for (int i = 0; i < NF; ++i) { w[i] = expf(w[i] - m); denom += w[i]; }
        const float inv = 1.0f / denom;

        float s = 0.0f;
        #pragma unroll
        for (int ff = 0; ff < NF; ++ff) s = fmaf(w[ff] * inv, fp[ff * FLEN + t], s);
        cs[t] = s;
    }

    float tap[FLEN];   // filled at k==0 (SGPRs via readlane, loop-invariant)

    #pragma unroll
    for (int k = 0; k < NTILE; ++k) {
        const int buf = k & 1;                       // static index (full unroll)
        const int tile = grp * NTILE + k;

        // ---- stage current tile's regs into LDS (vmcnt dependency wait here) ----
        lds4[buf][SWZ(d0)] = pv0;
        lds4[buf][SWZ(d1)] = pv1;
        if (has2) lds4[buf][SWZ(d2)] = pv2;

        // ---- issue NEXT tile's loads: they stay in flight across the barrier ----
        if (k + 1 < NTILE) {
            const int cb = (tile + 1) * TCELLS - 4;
            const unsigned g0 = (unsigned)(cb + d0);
            const unsigned g1 = (unsigned)(cb + d1);
            const unsigned g2 = (unsigned)(cb + d2);
            f32x4 n0 = (f32x4)(0.0f), n1 = n0, n2 = n0;
            if (g0 < ROWCELLS) n0 = __builtin_nontemporal_load(&xrow4[g0]);
            if (g1 < ROWCELLS) n1 = __builtin_nontemporal_load(&xrow4[g1]);
            if (has2 && g2 < ROWCELLS) n2 = __builtin_nontemporal_load(&xrow4[g2]);
            pv0 = n0; pv1 = n1; pv2 = n2;
        }

        LIGHT_BARRIER();   // lgkmcnt(0) only: LDS visible, globals stay in flight

        if (k == 0) {      // taps -> SGPRs after first barrier (cs now visible)
            const float tv = cs[tid & 31];
            #pragma unroll
            for (int t = 0; t < FLEN; ++t)
                tap[t] = __int_as_float(__builtin_amdgcn_readlane(__float_as_int(tv), t));
        }

        // ---- window: 10 swizzled b128 reads -> 40 floats, two halves ----
        float wA[20], wB[20];
        #pragma unroll
        for (int q = 0; q < 5; ++q) {
            const f32x4 v = lds4[buf][SWZ(2 * tid + q)];
            wA[4 * q + 0] = v.x; wA[4 * q + 1] = v.y;
            wA[4 * q + 2] = v.z; wA[4 * q + 3] = v.w;
        }
        #pragma unroll
        for (int q = 0; q < 5; ++q) {
            const f32x4 v = lds4[buf][SWZ(2 * tid + 5 + q)];
            wB[4 * q + 0] = v.x; wB[4 * q + 1] = v.y;
            wB[4 * q + 2] = v.z; wB[4 * q + 3] = v.w;
        }

        // out[8*tid + r] = sum_t tap[t] * w[r + 1 + t]
        float acc[RPT];
        #pragma unroll
        for (int r = 0; r < RPT; ++r) acc[r] = 0.0f;

        #pragma unroll
        for (int r = 0; r < RPT; ++r) {
            #pragma unroll
            for (int t = 0; t <= 18 - r; ++t)
                acc[r] = fmaf(tap[t], wA[r + 1 + t], acc[r]);
            #pragma unroll
            for (int t = 19 - r; t < FLEN; ++t)
                acc[r] = fmaf(tap[t], wB[r + t - 19], acc[r]);
        }

        // ---- nt stores (never drained at barriers; flushed at endpgm) ----
        f32x4* orow4 = orowbase4 + tile * TCELLS;
        f32x4 s0; s0.x = acc[0]; s0.y = acc[1]; s0.z = acc[2]; s0.w = acc[3];
        f32x4 s1; s1.x = acc[4]; s1.y = acc[5]; s1.z = acc[6]; s1.w = acc[7];
        __builtin_nontemporal_store(s0, &orow4[2 * tid + 0]);
        __builtin_nontemporal_store(s1, &orow4[2 * tid + 1]);
    }
}

extern "C" void kernel_launch(void* const* d_in, const int* in_sizes, int n_in,
                              void* d_out, int out_size, void* d_ws, size_t ws_size,
                              hipStream_t stream) {
    const float* x        = (const float*)d_in[0];
    const float* features = (const float*)d_in[1];
    const float* fp       = (const float*)d_in[2];
    const float* W1       = (const float*)d_in[3];
    const float* b1       = (const float*)d_in[4];
    const float* W2       = (const float*)d_in[5];
    const float* b2       = (const float*)d_in[6];
    float* out = (float*)d_out;

    const int grid = BB * GRPS;  // 64 * 16 = 1024 blocks, ~4/CU, all resident
    adaptive_filter_fused<<<grid, TPB, 0, stream>>>(x, features, fp, W1, b1, W2, b2, out);
}